// Round 1
// baseline (106.853 us; speedup 1.0000x reference)
//
#include <hip/hip_runtime.h>

#define K_BINS 1025
#define T_LEN  2000
#define B_SZ   32
#define NF     128

__device__ __forceinline__ float softplusf(float x) {
    // matches jax.nn.softplus = max(x,0) + log1p(exp(-|x|))
    return fmaxf(x, 0.0f) + log1pf(expf(-fabsf(x)));
}

// One tiny block: precompute per-filter params into workspace.
__global__ void fb_setup_kernel(const float* __restrict__ cf,
                                const float* __restrict__ bwv,
                                const float* __restrict__ fs,
                                float4* __restrict__ params,
                                int2*   __restrict__ krange) {
    int f = threadIdx.x;
    if (f >= NF) return;
    float c  = cf[f];
    float bw = softplusf(bwv[f]) + 0.001f;
    float s0 = softplusf(fs[2 * f])     + 0.1f;
    float s1 = softplusf(fs[2 * f + 1]) + 0.1f;
    float left  = c - bw * s0;
    float right = c + bw * s1;
    float invcl = 1.0f / (c - left + 1e-8f);
    float invrc = 1.0f / (right - c + 1e-8f);
    int klo = (int)ceilf(left);   klo = klo < 0 ? 0 : klo;
    int khi = (int)floorf(right); khi = khi > (K_BINS - 1) ? (K_BINS - 1) : khi;
    params[f] = make_float4(left, invcl, c, invrc);
    krange[f] = make_int2(klo, khi);
}

// out[b2, t, f2] = filtered[b', f', t], f2 = 4*b' + (f'>>5), b2 = f'&31.
// Thread owns (b2, b', t) -> computes f' = b2 + 32w for w=0..3 -> one float4 store.
// Lane map: b' = 4*bz + (lane&3), t = 16*bx + (lane>>2)  => wave stores are full 64B lines.
__global__ __launch_bounds__(256) void fb_apply_kernel(
        const float*  __restrict__ spec,
        const float4* __restrict__ params,
        const int2*   __restrict__ krange,
        float*        __restrict__ out) {
    const int lane = threadIdx.x & 63;
    const int wid  = threadIdx.x >> 6;
    const int b2   = blockIdx.y * 4 + wid;            // 0..31 (filter low bits)
    const int bp   = blockIdx.z * 4 + (lane & 3);     // batch b', 0..31
    const int t    = blockIdx.x * 16 + (lane >> 2);   // 0..1999 (125*16 == 2000, no tail)

    const float* specb = spec + (size_t)bp * (K_BINS * T_LEN) + t;

    float acc[4];
#pragma unroll
    for (int w = 0; w < 4; ++w) {
        const int f = b2 + 32 * w;
        const float4 p = params[f];   // {left, invcl, center, invrc} — wave-uniform
        const int2  kr = krange[f];   // wave-uniform loop bounds, no divergence
        float a = 0.0f;
        const float* sp = specb + (size_t)kr.x * T_LEN;
        for (int k = kr.x; k <= kr.y; ++k) {
            float fk  = (float)k;
            float wgt = (fk <= p.z) ? (fk - p.x) * p.y
                                    : fmaf(-(fk - p.z), p.w, 1.0f);
            a = fmaf(wgt, *sp, a);
            sp += T_LEN;
        }
        acc[w] = a;
    }
    float4 o = make_float4(acc[0], acc[1], acc[2], acc[3]);
    *reinterpret_cast<float4*>(out + (size_t)b2 * (T_LEN * NF) + t * NF + 4 * bp) = o;
}

extern "C" void kernel_launch(void* const* d_in, const int* in_sizes, int n_in,
                              void* d_out, int out_size, void* d_ws, size_t ws_size,
                              hipStream_t stream) {
    const float* spec = (const float*)d_in[0];   // (32, 1025, 2000) f32
    const float* cf   = (const float*)d_in[1];   // (128,)
    const float* bwv  = (const float*)d_in[2];   // (128,)
    const float* fs   = (const float*)d_in[3];   // (128, 2)

    float*  out    = (float*)d_out;              // (32, 2000, 128) f32
    float4* params = (float4*)d_ws;
    int2*   krange = (int2*)((char*)d_ws + NF * sizeof(float4));

    fb_setup_kernel<<<1, 128, 0, stream>>>(cf, bwv, fs, params, krange);
    fb_apply_kernel<<<dim3(125, 8, 8), 256, 0, stream>>>(spec, params, krange, out);
}